// Round 6
// baseline (371.149 us; speedup 1.0000x reference)
//
#include <hip/hip_runtime.h>
#include <math.h>

// Causal self-attention, B=4 T=2048 E=1024 H=16 D=64.
// R6: attention back to 128-q blocks (4 blocks/CU) with a balanced qt schedule
//     (every CU's resident blocks sum to identical tile work: qt table
//     15..12 / 8..11 / 7..4 / 0..3 over 64-block batches). GEMM gets XCD
//     supertiling (bm-slab per XCD -> each A-tile L2-filled once).

using short8 = __attribute__((ext_vector_type(8))) short;
using f32x4  = __attribute__((ext_vector_type(4))) float;

__device__ __forceinline__ ushort f2bf(float f) {
    union { float f; unsigned u; } x{f};
    unsigned r = x.u + 0x7fffu + ((x.u >> 16) & 1u);   // RNE
    return (ushort)(r >> 16);
}
// pack two f32 -> two bf16 (round-half-up in magnitude; <=1 ulp) in 3 VALU
__device__ __forceinline__ unsigned pack_bf16_ru(float a, float b) {
    union { float f; unsigned u; } x{a}, y{b};
    return __builtin_amdgcn_perm(y.u + 0x8000u, x.u + 0x8000u, 0x07060302u);
}

__device__ __forceinline__ void gload_lds16(const void* g, void* l) {
    __builtin_amdgcn_global_load_lds(
        (const __attribute__((address_space(1))) void*)g,
        (__attribute__((address_space(3))) void*)l, 16, 0, 0);
}

// ---------------- fp32 -> bf16 convert (x and w in one launch) ----------------
__global__ void cvt_all(const float* __restrict__ x, const float* __restrict__ w,
                        ushort* __restrict__ xb, ushort* __restrict__ wb) {
    int i = blockIdx.x * blockDim.x + threadIdx.x;
    const float* src; ushort* dst; int j;
    if (i < 2097152) { src = x; dst = xb; j = i; }
    else             { src = w; dst = wb; j = i - 2097152; if (j >= 786432) return; }
    float4 v = ((const float4*)src)[j];
    ushort4 o;
    o.x = f2bf(v.x); o.y = f2bf(v.y); o.z = f2bf(v.z); o.w = f2bf(v.w);
    ((ushort4*)dst)[j] = o;
}

// ---------------- QKV GEMM ----------------
// M=8192 N=3072 K=1024. 128x128 tile, BK=64, global_load_lds + swizzle.
// Grid 1536 1-D: xcd=id&7 owns bm slab xcd*8..+7 (A-tiles filled once per L2).
__global__ __launch_bounds__(256) void qkv_gemm(
    const ushort* __restrict__ A, const ushort* __restrict__ W,
    const float* __restrict__ bias,
    ushort* __restrict__ Qo, ushort* __restrict__ Ko, ushort* __restrict__ Vt)
{
    __shared__ ushort As[128 * 64];
    __shared__ ushort Ws[128 * 64];
    const int id = (int)blockIdx.x;
    const int xcd = id & 7, s = id >> 3;          // s: 0..191
    const int bm = xcd * 8 + (s & 7);             // 8-row slab per XCD
    const int bn = s >> 3;                        // 0..23
    const int tid = threadIdx.x;
    const int wave = tid >> 6, lane = tid & 63;
    const int quad = lane >> 4, l16 = lane & 15, l7 = l16 & 7;
    const int wm = (wave >> 1) * 64, wn = (wave & 1) * 64;

    const ushort* Abase = A + (size_t)(bm * 128) * 1024;
    const ushort* Wbase = W + (size_t)(bn * 128) * 1024;

    f32x4 acc[4][4];
#pragma unroll
    for (int i = 0; i < 4; i++)
#pragma unroll
        for (int j = 0; j < 4; j++) acc[i][j] = (f32x4){0.f, 0.f, 0.f, 0.f};

    for (int k0 = 0; k0 < 1024; k0 += 64) {
        __syncthreads();
#pragma unroll
        for (int j = 0; j < 4; j++) {
            const int rb = wave * 32 + j * 8;
            const int r  = rb + (lane >> 3);
            const int cc = (lane & 7) ^ (r & 7);
            gload_lds16(Abase + (size_t)r * 1024 + k0 + cc * 8, &As[rb * 64]);
            gload_lds16(Wbase + (size_t)r * 1024 + k0 + cc * 8, &Ws[rb * 64]);
        }
        __syncthreads();
        short8 af[4][2], wf[4][2];
#pragma unroll
        for (int t = 0; t < 4; t++)
#pragma unroll
            for (int kg = 0; kg < 2; kg++) {
                const int pc = ((kg * 4 + quad) ^ l7) * 8;
                af[t][kg] = *(const short8*)&As[(wm + t * 16 + l16) * 64 + pc];
                wf[t][kg] = *(const short8*)&Ws[(wn + t * 16 + l16) * 64 + pc];
            }
#pragma unroll
        for (int kg = 0; kg < 2; kg++)
#pragma unroll
            for (int tm = 0; tm < 4; tm++)
#pragma unroll
                for (int tn = 0; tn < 4; tn++)
                    acc[tm][tn] = __builtin_amdgcn_mfma_f32_16x16x32_bf16(af[tm][kg], wf[tn][kg], acc[tm][tn], 0, 0, 0);
    }

    const float SCALE_Q = 0.125f * 1.4426950408889634f;
#pragma unroll
    for (int tn = 0; tn < 4; tn++) {
        const int n = bn * 128 + wn + tn * 16 + l16;
        const float bv = bias[n];
#pragma unroll
        for (int tm = 0; tm < 4; tm++) {
            const int m0 = bm * 128 + wm + tm * 16 + quad * 4;
            const int b0 = m0 >> 11, t0 = m0 & 2047;
            if (n < 1024) {
                const int h = n >> 6, d = n & 63;
#pragma unroll
                for (int r = 0; r < 4; r++)
                    Qo[((size_t)(b0 * 16 + h) * 2048 + t0 + r) * 64 + d] = f2bf((acc[tm][tn][r] + bv) * SCALE_Q);
            } else if (n < 2048) {
                const int c = n - 1024, h = c >> 6, d = c & 63;
#pragma unroll
                for (int r = 0; r < 4; r++)
                    Ko[((size_t)(b0 * 16 + h) * 2048 + t0 + r) * 64 + d] = f2bf(acc[tm][tn][r] + bv);
            } else {
                const int c = n - 2048, h = c >> 6, d = c & 63;
                uint2 pk;
                pk.x = pack_bf16_ru(acc[tm][tn][0] + bv, acc[tm][tn][1] + bv);
                pk.y = pack_bf16_ru(acc[tm][tn][2] + bv, acc[tm][tn][3] + bv);
                *(uint2*)&Vt[((size_t)(b0 * 16 + h) * 64 + d) * 2048 + t0] = pk;
            }
        }
    }
}

// ---------------- Flash attention (fixed-max softmax, 128-q blocks, balanced) ----------------
// Block = 128 q-rows x (bh). Wave w owns q-groups qt*128+w*16 and +64.
// qt schedule: batches s=0..15 -> [15,14,13,12, 8,9,10,11, 7,6,5,4, 0,1,2,3]
// so each CU's 4 round-robin blocks sum to identical tile work (68).
__global__ __launch_bounds__(256, 4) void attn_fwd(
    const ushort* __restrict__ Q, const ushort* __restrict__ K,
    const ushort* __restrict__ Vt, float* __restrict__ out)
{
    __shared__ ushort Ks[2][64 * 64];
    __shared__ ushort Vs[2][64 * 64];
    __shared__ ushort Ps[4][16 * 64];   // per-wave, reused per qg
    const int id = (int)blockIdx.x;     // 1024 blocks
    const int bh = id & 63;             // id%8 = bh%8 -> head's 16 blocks on one XCD
    const int s  = id >> 6;             // 0..15
    const int g = s >> 2, r4 = s & 3;
    const int qt = (g == 0) ? 15 - r4 : (g == 1) ? 8 + r4 : (g == 2) ? 7 - r4 : r4;
    const int b = bh >> 4, h = bh & 15;
    const int wave = threadIdx.x >> 6, lane = threadIdx.x & 63;
    const int quad = lane >> 4, l16 = lane & 15, l7 = l16 & 7;

    const ushort* Kbh = K  + (size_t)bh * 2048 * 64;
    const ushort* Vbh = Vt + (size_t)bh * 64 * 2048;
    ushort* Pw = Ps[wave];

    int qb[2];
    qb[0] = qt * 128 + wave * 16;
    qb[1] = qb[0] + 64;

    short8 qf[2][2];
#pragma unroll
    for (int qg = 0; qg < 2; qg++) {
        const ushort* Qp = Q + ((size_t)bh * 2048 + qb[qg] + l16) * 64;
        qf[qg][0] = *(const short8*)(Qp + quad * 8);
        qf[qg][1] = *(const short8*)(Qp + 32 + quad * 8);
    }

    f32x4 o[2][4];
#pragma unroll
    for (int qg = 0; qg < 2; qg++)
#pragma unroll
        for (int dg = 0; dg < 4; dg++) o[qg][dg] = (f32x4){0.f, 0.f, 0.f, 0.f};
    float lsum[2] = {0.f, 0.f};

    const int ntiles = 2 * qt + 2;

#define STAGE(k0_, bf_)                                                              \
    {                                                                                \
        _Pragma("unroll")                                                            \
        for (int j = 0; j < 2; j++) {                                                \
            const int rb = wave * 16 + j * 8;                                        \
            const int r  = rb + (lane >> 3);                                         \
            const int cc = (lane & 7) ^ (r & 7);                                     \
            gload_lds16(Kbh + (size_t)((k0_) + r) * 64 + cc * 8, &Ks[bf_][rb * 64]); \
            gload_lds16(Vbh + (size_t)r * 2048 + (k0_) + cc * 8, &Vs[bf_][rb * 64]); \
        }                                                                            \
    }

    STAGE(0, 0);
    int buf = 0, k0 = 0;
    for (int it = 0; it < ntiles; ++it, k0 += 64, buf ^= 1) {
        __syncthreads();
        if (it + 1 < ntiles) STAGE(k0 + 64, buf ^ 1);
        if (k0 > qb[1] + 15) continue;     // uniform barrier count preserved

        const bool act0 = k0 <= qb[0] + 15;   // qg1 always active here

        short8 kf[4][2];
#pragma unroll
        for (int t = 0; t < 4; t++)
#pragma unroll
            for (int dh = 0; dh < 2; dh++)
                kf[t][dh] = *(const short8*)&Ks[buf][(t * 16 + l16) * 64 + (((dh * 4 + quad) ^ l7) * 8)];
        short8 vf[2][4];
#pragma unroll
        for (int kg = 0; kg < 2; kg++) {
            const int pc = ((kg * 4 + quad) ^ l7) * 8;
#pragma unroll
            for (int dg = 0; dg < 4; dg++)
                vf[kg][dg] = *(const short8*)&Vs[buf][(dg * 16 + l16) * 64 + pc];
        }

#pragma unroll
        for (int qg = 0; qg < 2; qg++) {
            if (qg == 0 && !act0) continue;
            f32x4 sc[4];
#pragma unroll
            for (int t = 0; t < 4; t++) {
                f32x4 z = (f32x4){0.f, 0.f, 0.f, 0.f};
                z = __builtin_amdgcn_mfma_f32_16x16x32_bf16(kf[t][0], qf[qg][0], z, 0, 0, 0);
                z = __builtin_amdgcn_mfma_f32_16x16x32_bf16(kf[t][1], qf[qg][1], z, 0, 0, 0);
                sc[t] = z;
            }
            const int q = qb[qg] + l16;
            float p[16], ps = 0.f;
            if (k0 + 63 > qb[qg]) {          // diagonal region: mask
#pragma unroll
                for (int t = 0; t < 4; t++)
#pragma unroll
                    for (int r = 0; r < 4; r++) {
                        const int key = k0 + t * 16 + quad * 4 + r;
                        const float sv = (key <= q) ? sc[t][r] : -INFINITY;
                        p[t * 4 + r] = __builtin_amdgcn_exp2f(sv);
                    }
            } else {
#pragma unroll
                for (int t = 0; t < 4; t++)
#pragma unroll
                    for (int r = 0; r < 4; r++)
                        p[t * 4 + r] = __builtin_amdgcn_exp2f(sc[t][r]);
            }
#pragma unroll
            for (int i = 0; i < 16; i++) ps += p[i];
            lsum[qg] += ps;
            // P -> LDS (row l16, chunk-swizzled), then same-wave readback
#pragma unroll
            for (int t = 0; t < 4; t++) {
                uint2 pk;
                pk.x = pack_bf16_ru(p[t * 4 + 0], p[t * 4 + 1]);
                pk.y = pack_bf16_ru(p[t * 4 + 2], p[t * 4 + 3]);
                const int pc = ((2 * t + (quad >> 1)) ^ l7) * 8 + (quad & 1) * 4;
                *(uint2*)(Pw + l16 * 64 + pc) = pk;
            }
#pragma unroll
            for (int kg = 0; kg < 2; kg++) {
                short8 pf = *(const short8*)(Pw + l16 * 64 + (((kg * 4 + quad) ^ l7) * 8));
#pragma unroll
                for (int dg = 0; dg < 4; dg++)
                    o[qg][dg] = __builtin_amdgcn_mfma_f32_16x16x32_bf16(vf[kg][dg], pf, o[qg][dg], 0, 0, 0);
            }
        }
    }
#undef STAGE

    // final l reduction across quads (same q column), then store O^T
#pragma unroll
    for (int qg = 0; qg < 2; qg++) {
        float l = lsum[qg];
        l += __shfl_xor(l, 16);
        l += __shfl_xor(l, 32);
        const float rinv = 1.f / l;
        float* op = out + ((size_t)(b * 2048 + qb[qg] + l16)) * 1024 + h * 64;
#pragma unroll
        for (int dg = 0; dg < 4; dg++) {
            float4 v;
            v.x = o[qg][dg][0] * rinv; v.y = o[qg][dg][1] * rinv;
            v.z = o[qg][dg][2] * rinv; v.w = o[qg][dg][3] * rinv;
            *(float4*)(op + dg * 16 + quad * 4) = v;
        }
    }
}

// ---------------- launch ----------------
extern "C" void kernel_launch(void* const* d_in, const int* in_sizes, int n_in,
                              void* d_out, int out_size, void* d_ws, size_t ws_size,
                              hipStream_t stream) {
    const float* x    = (const float*)d_in[0];
    const float* w    = (const float*)d_in[1];
    const float* bias = (const float*)d_in[2];

    ushort* xb  = (ushort*)d_ws;                 // 8192x1024 bf16
    ushort* wb  = xb + 8388608;                  // 3072x1024 bf16
    ushort* Qb  = wb + 3145728;                  // [B,H,T,D] (pre-scaled)
    ushort* Kb  = Qb + 8388608;                  // [B,H,T,D]
    ushort* Vtb = Kb + 8388608;                  // [B,H,D,T]

    cvt_all<<<11264, 256, 0, stream>>>(x, w, xb, wb);
    qkv_gemm<<<1536, 256, 0, stream>>>(xb, wb, bias, Qb, Kb, Vtb);
    attn_fwd<<<1024, 256, 0, stream>>>(Qb, Kb, Vtb, (float*)d_out);
}

// Round 7
// 220.245 us; speedup vs baseline: 1.6852x; 1.6852x over previous
//
#include <hip/hip_runtime.h>
#include <math.h>

// Causal self-attention, B=4 T=2048 E=1024 H=16 D=64.
// R7: R6 minus the attn __launch_bounds__(256,4) — that hint squeezed VGPR to
//     64 and caused scratch spills (530 MB HBM writes, 219 us). Natural alloc
//     (~104 VGPR) already allows 4 waves/EU + 4 blocks/CU at 40 KB LDS.
//     Keeps: balanced qt schedule (per-CU tile work uniform at 68), XCD-
//     clustered bh, XCD-supertiled GEMM, packed bf16 cvt.

using short8 = __attribute__((ext_vector_type(8))) short;
using f32x4  = __attribute__((ext_vector_type(4))) float;

__device__ __forceinline__ ushort f2bf(float f) {
    union { float f; unsigned u; } x{f};
    unsigned r = x.u + 0x7fffu + ((x.u >> 16) & 1u);   // RNE
    return (ushort)(r >> 16);
}
// pack two f32 -> two bf16 (round-half-up in magnitude; <=1 ulp) in 3 VALU
__device__ __forceinline__ unsigned pack_bf16_ru(float a, float b) {
    union { float f; unsigned u; } x{a}, y{b};
    return __builtin_amdgcn_perm(y.u + 0x8000u, x.u + 0x8000u, 0x07060302u);
}

__device__ __forceinline__ void gload_lds16(const void* g, void* l) {
    __builtin_amdgcn_global_load_lds(
        (const __attribute__((address_space(1))) void*)g,
        (__attribute__((address_space(3))) void*)l, 16, 0, 0);
}

// ---------------- fp32 -> bf16 convert (x and w in one launch) ----------------
__global__ void cvt_all(const float* __restrict__ x, const float* __restrict__ w,
                        ushort* __restrict__ xb, ushort* __restrict__ wb) {
    int i = blockIdx.x * blockDim.x + threadIdx.x;
    const float* src; ushort* dst; int j;
    if (i < 2097152) { src = x; dst = xb; j = i; }
    else             { src = w; dst = wb; j = i - 2097152; if (j >= 786432) return; }
    float4 v = ((const float4*)src)[j];
    ushort4 o;
    o.x = f2bf(v.x); o.y = f2bf(v.y); o.z = f2bf(v.z); o.w = f2bf(v.w);
    ((ushort4*)dst)[j] = o;
}

// ---------------- QKV GEMM ----------------
// M=8192 N=3072 K=1024. 128x128 tile, BK=64, global_load_lds + swizzle.
// Grid 1536 1-D: xcd=id&7 owns bm slab xcd*8..+7 (A-tiles filled once per L2).
__global__ __launch_bounds__(256) void qkv_gemm(
    const ushort* __restrict__ A, const ushort* __restrict__ W,
    const float* __restrict__ bias,
    ushort* __restrict__ Qo, ushort* __restrict__ Ko, ushort* __restrict__ Vt)
{
    __shared__ ushort As[128 * 64];
    __shared__ ushort Ws[128 * 64];
    const int id = (int)blockIdx.x;
    const int xcd = id & 7, s = id >> 3;          // s: 0..191
    const int bm = xcd * 8 + (s & 7);             // 8-row slab per XCD
    const int bn = s >> 3;                        // 0..23
    const int tid = threadIdx.x;
    const int wave = tid >> 6, lane = tid & 63;
    const int quad = lane >> 4, l16 = lane & 15, l7 = l16 & 7;
    const int wm = (wave >> 1) * 64, wn = (wave & 1) * 64;

    const ushort* Abase = A + (size_t)(bm * 128) * 1024;
    const ushort* Wbase = W + (size_t)(bn * 128) * 1024;

    f32x4 acc[4][4];
#pragma unroll
    for (int i = 0; i < 4; i++)
#pragma unroll
        for (int j = 0; j < 4; j++) acc[i][j] = (f32x4){0.f, 0.f, 0.f, 0.f};

    for (int k0 = 0; k0 < 1024; k0 += 64) {
        __syncthreads();
#pragma unroll
        for (int j = 0; j < 4; j++) {
            const int rb = wave * 32 + j * 8;
            const int r  = rb + (lane >> 3);
            const int cc = (lane & 7) ^ (r & 7);
            gload_lds16(Abase + (size_t)r * 1024 + k0 + cc * 8, &As[rb * 64]);
            gload_lds16(Wbase + (size_t)r * 1024 + k0 + cc * 8, &Ws[rb * 64]);
        }
        __syncthreads();
        short8 af[4][2], wf[4][2];
#pragma unroll
        for (int t = 0; t < 4; t++)
#pragma unroll
            for (int kg = 0; kg < 2; kg++) {
                const int pc = ((kg * 4 + quad) ^ l7) * 8;
                af[t][kg] = *(const short8*)&As[(wm + t * 16 + l16) * 64 + pc];
                wf[t][kg] = *(const short8*)&Ws[(wn + t * 16 + l16) * 64 + pc];
            }
#pragma unroll
        for (int kg = 0; kg < 2; kg++)
#pragma unroll
            for (int tm = 0; tm < 4; tm++)
#pragma unroll
                for (int tn = 0; tn < 4; tn++)
                    acc[tm][tn] = __builtin_amdgcn_mfma_f32_16x16x32_bf16(af[tm][kg], wf[tn][kg], acc[tm][tn], 0, 0, 0);
    }

    const float SCALE_Q = 0.125f * 1.4426950408889634f;
#pragma unroll
    for (int tn = 0; tn < 4; tn++) {
        const int n = bn * 128 + wn + tn * 16 + l16;
        const float bv = bias[n];
#pragma unroll
        for (int tm = 0; tm < 4; tm++) {
            const int m0 = bm * 128 + wm + tm * 16 + quad * 4;
            const int b0 = m0 >> 11, t0 = m0 & 2047;
            if (n < 1024) {
                const int h = n >> 6, d = n & 63;
#pragma unroll
                for (int r = 0; r < 4; r++)
                    Qo[((size_t)(b0 * 16 + h) * 2048 + t0 + r) * 64 + d] = f2bf((acc[tm][tn][r] + bv) * SCALE_Q);
            } else if (n < 2048) {
                const int c = n - 1024, h = c >> 6, d = c & 63;
#pragma unroll
                for (int r = 0; r < 4; r++)
                    Ko[((size_t)(b0 * 16 + h) * 2048 + t0 + r) * 64 + d] = f2bf(acc[tm][tn][r] + bv);
            } else {
                const int c = n - 2048, h = c >> 6, d = c & 63;
                uint2 pk;
                pk.x = pack_bf16_ru(acc[tm][tn][0] + bv, acc[tm][tn][1] + bv);
                pk.y = pack_bf16_ru(acc[tm][tn][2] + bv, acc[tm][tn][3] + bv);
                *(uint2*)&Vt[((size_t)(b0 * 16 + h) * 64 + d) * 2048 + t0] = pk;
            }
        }
    }
}

// ---------------- Flash attention (fixed-max softmax, 128-q blocks, balanced) ----------------
// Block = 128 q-rows x (bh). Wave w owns q-groups qt*128+w*16 and +64.
// qt schedule: batches s=0..15 -> [15,14,13,12, 8,9,10,11, 7,6,5,4, 0,1,2,3]
// so each CU's 4 round-robin blocks sum to identical tile work (68).
// NOTE: no min-waves launch bound — (256,4) forced VGPR 104->64 and spilled
// (530 MB scratch writes). Natural alloc gives 4 waves/EU anyway.
__global__ __launch_bounds__(256) void attn_fwd(
    const ushort* __restrict__ Q, const ushort* __restrict__ K,
    const ushort* __restrict__ Vt, float* __restrict__ out)
{
    __shared__ ushort Ks[2][64 * 64];
    __shared__ ushort Vs[2][64 * 64];
    __shared__ ushort Ps[4][16 * 64];   // per-wave, reused per qg
    const int id = (int)blockIdx.x;     // 1024 blocks
    const int bh = id & 63;             // id%8 = bh%8 -> head's 16 blocks on one XCD
    const int s  = id >> 6;             // 0..15
    const int g = s >> 2, r4 = s & 3;
    const int qt = (g == 0) ? 15 - r4 : (g == 1) ? 8 + r4 : (g == 2) ? 7 - r4 : r4;
    const int b = bh >> 4, h = bh & 15;
    const int wave = threadIdx.x >> 6, lane = threadIdx.x & 63;
    const int quad = lane >> 4, l16 = lane & 15, l7 = l16 & 7;

    const ushort* Kbh = K  + (size_t)bh * 2048 * 64;
    const ushort* Vbh = Vt + (size_t)bh * 64 * 2048;
    ushort* Pw = Ps[wave];

    int qb[2];
    qb[0] = qt * 128 + wave * 16;
    qb[1] = qb[0] + 64;

    short8 qf[2][2];
#pragma unroll
    for (int qg = 0; qg < 2; qg++) {
        const ushort* Qp = Q + ((size_t)bh * 2048 + qb[qg] + l16) * 64;
        qf[qg][0] = *(const short8*)(Qp + quad * 8);
        qf[qg][1] = *(const short8*)(Qp + 32 + quad * 8);
    }

    f32x4 o[2][4];
#pragma unroll
    for (int qg = 0; qg < 2; qg++)
#pragma unroll
        for (int dg = 0; dg < 4; dg++) o[qg][dg] = (f32x4){0.f, 0.f, 0.f, 0.f};
    float lsum[2] = {0.f, 0.f};

    const int ntiles = 2 * qt + 2;

#define STAGE(k0_, bf_)                                                              \
    {                                                                                \
        _Pragma("unroll")                                                            \
        for (int j = 0; j < 2; j++) {                                                \
            const int rb = wave * 16 + j * 8;                                        \
            const int r  = rb + (lane >> 3);                                         \
            const int cc = (lane & 7) ^ (r & 7);                                     \
            gload_lds16(Kbh + (size_t)((k0_) + r) * 64 + cc * 8, &Ks[bf_][rb * 64]); \
            gload_lds16(Vbh + (size_t)r * 2048 + (k0_) + cc * 8, &Vs[bf_][rb * 64]); \
        }                                                                            \
    }

    STAGE(0, 0);
    int buf = 0, k0 = 0;
    for (int it = 0; it < ntiles; ++it, k0 += 64, buf ^= 1) {
        __syncthreads();
        if (it + 1 < ntiles) STAGE(k0 + 64, buf ^ 1);
        if (k0 > qb[1] + 15) continue;     // uniform barrier count preserved

        const bool act0 = k0 <= qb[0] + 15;   // qg1 always active here

        short8 kf[4][2];
#pragma unroll
        for (int t = 0; t < 4; t++)
#pragma unroll
            for (int dh = 0; dh < 2; dh++)
                kf[t][dh] = *(const short8*)&Ks[buf][(t * 16 + l16) * 64 + (((dh * 4 + quad) ^ l7) * 8)];
        short8 vf[2][4];
#pragma unroll
        for (int kg = 0; kg < 2; kg++) {
            const int pc = ((kg * 4 + quad) ^ l7) * 8;
#pragma unroll
            for (int dg = 0; dg < 4; dg++)
                vf[kg][dg] = *(const short8*)&Vs[buf][(dg * 16 + l16) * 64 + pc];
        }

#pragma unroll
        for (int qg = 0; qg < 2; qg++) {
            if (qg == 0 && !act0) continue;
            f32x4 sc[4];
#pragma unroll
            for (int t = 0; t < 4; t++) {
                f32x4 z = (f32x4){0.f, 0.f, 0.f, 0.f};
                z = __builtin_amdgcn_mfma_f32_16x16x32_bf16(kf[t][0], qf[qg][0], z, 0, 0, 0);
                z = __builtin_amdgcn_mfma_f32_16x16x32_bf16(kf[t][1], qf[qg][1], z, 0, 0, 0);
                sc[t] = z;
            }
            const int q = qb[qg] + l16;
            float p[16], ps = 0.f;
            if (k0 + 63 > qb[qg]) {          // diagonal region: mask
#pragma unroll
                for (int t = 0; t < 4; t++)
#pragma unroll
                    for (int r = 0; r < 4; r++) {
                        const int key = k0 + t * 16 + quad * 4 + r;
                        const float sv = (key <= q) ? sc[t][r] : -INFINITY;
                        p[t * 4 + r] = __builtin_amdgcn_exp2f(sv);
                    }
            } else {
#pragma unroll
                for (int t = 0; t < 4; t++)
#pragma unroll
                    for (int r = 0; r < 4; r++)
                        p[t * 4 + r] = __builtin_amdgcn_exp2f(sc[t][r]);
            }
#pragma unroll
            for (int i = 0; i < 16; i++) ps += p[i];
            lsum[qg] += ps;
            // P -> LDS (row l16, chunk-swizzled), then same-wave readback
#pragma unroll
            for (int t = 0; t < 4; t++) {
                uint2 pk;
                pk.x = pack_bf16_ru(p[t * 4 + 0], p[t * 4 + 1]);
                pk.y = pack_bf16_ru(p[t * 4 + 2], p[t * 4 + 3]);
                const int pc = ((2 * t + (quad >> 1)) ^ l7) * 8 + (quad & 1) * 4;
                *(uint2*)(Pw + l16 * 64 + pc) = pk;
            }
#pragma unroll
            for (int kg = 0; kg < 2; kg++) {
                short8 pf = *(const short8*)(Pw + l16 * 64 + (((kg * 4 + quad) ^ l7) * 8));
#pragma unroll
                for (int dg = 0; dg < 4; dg++)
                    o[qg][dg] = __builtin_amdgcn_mfma_f32_16x16x32_bf16(vf[kg][dg], pf, o[qg][dg], 0, 0, 0);
            }
        }
    }
#undef STAGE

    // final l reduction across quads (same q column), then store O^T
#pragma unroll
    for (int qg = 0; qg < 2; qg++) {
        float l = lsum[qg];
        l += __shfl_xor(l, 16);
        l += __shfl_xor(l, 32);
        const float rinv = 1.f / l;
        float* op = out + ((size_t)(b * 2048 + qb[qg] + l16)) * 1024 + h * 64;
#pragma unroll
        for (int dg = 0; dg < 4; dg++) {
            float4 v;
            v.x = o[qg][dg][0] * rinv; v.y = o[qg][dg][1] * rinv;
            v.z = o[qg][dg][2] * rinv; v.w = o[qg][dg][3] * rinv;
            *(float4*)(op + dg * 16 + quad * 4) = v;
        }
    }
}

// ---------------- launch ----------------
extern "C" void kernel_launch(void* const* d_in, const int* in_sizes, int n_in,
                              void* d_out, int out_size, void* d_ws, size_t ws_size,
                              hipStream_t stream) {
    const float* x    = (const float*)d_in[0];
    const float* w    = (const float*)d_in[1];
    const float* bias = (const float*)d_in[2];

    ushort* xb  = (ushort*)d_ws;                 // 8192x1024 bf16
    ushort* wb  = xb + 8388608;                  // 3072x1024 bf16
    ushort* Qb  = wb + 3145728;                  // [B,H,T,D] (pre-scaled)
    ushort* Kb  = Qb + 8388608;                  // [B,H,T,D]
    ushort* Vtb = Kb + 8388608;                  // [B,H,D,T]

    cvt_all<<<11264, 256, 0, stream>>>(x, w, xb, wb);
    qkv_gemm<<<1536, 256, 0, stream>>>(xb, wb, bias, Qb, Kb, Vtb);
    attn_fwd<<<1024, 256, 0, stream>>>(Qb, Kb, Vtb, (float*)d_out);
}